// Round 3
// baseline (26272.238 us; speedup 1.0000x reference)
//
#include <hip/hip_runtime.h>

typedef unsigned short u16;
typedef unsigned int u32;
typedef unsigned long long u64;
typedef __attribute__((ext_vector_type(8))) short bf16x8;
typedef __attribute__((ext_vector_type(4))) float f32x4;

#define S_LEN 5120
#define NB 16
#define UA 384
#define UB 64
#define GA 1152
#define CAPP (1 << 20)

__device__ __forceinline__ float bf2f(u16 u) { return __uint_as_float(((u32)u) << 16); }
__device__ __forceinline__ u16 f2bf(float f) {
    u32 x = __float_as_uint(f);
    return (u16)((x + 0x7fffu + ((x >> 16) & 1u)) >> 16);
}
__device__ __forceinline__ float blo(u32 w) { return __uint_as_float(w << 16); }
__device__ __forceinline__ float bhi(u32 w) { return __uint_as_float(w & 0xffff0000u); }
__device__ __forceinline__ float sigm(float x) { return 1.f / (1.f + __expf(-x)); }
__device__ __forceinline__ float tanh_(float x) { float e = __expf(2.f * x); return 1.f - 2.f / (e + 1.f); }
__device__ __forceinline__ uint2 pack4(float4 v) {
    return make_uint2((u32)f2bf(v.x) | ((u32)f2bf(v.y) << 16),
                      (u32)f2bf(v.z) | ((u32)f2bf(v.w) << 16));
}

// ---------------- convert grua_wih to bf16 ----------------
__global__ __launch_bounds__(256) void k_cvt(const float* __restrict__ src, u16* __restrict__ dst) {
    int i = blockIdx.x * 256 + threadIdx.x;
    dst[i] = f2bf(src[i]);
}

// ---------------- frame-rate network ----------------
__global__ __launch_bounds__(128) void k_frame1(const float* __restrict__ features, const int* __restrict__ periods,
                                                const float* __restrict__ pemb, const float* __restrict__ w,
                                                const float* __restrict__ bias, float* __restrict__ c1) {
    __shared__ float fin[3][84];
    int t = blockIdx.x, b = blockIdx.y, o = threadIdx.x;
    for (int i = threadIdx.x; i < 252; i += 128) {
        int kk = i / 84, ci = i % 84, tt = t + kk;
        float v;
        if (ci < 20) v = features[(b * 36 + tt) * 20 + ci];
        else v = pemb[periods[b * 36 + tt] * 64 + (ci - 20)];
        fin[kk][ci] = v;
    }
    __syncthreads();
    float acc = bias[o];
    for (int kk = 0; kk < 3; kk++)
        for (int ci = 0; ci < 84; ci++)
            acc = fmaf(fin[kk][ci], w[o * 252 + ci * 3 + kk], acc);
    c1[(b * 34 + t) * 128 + o] = tanh_(acc);
}

__global__ __launch_bounds__(128) void k_frame2(const float* __restrict__ c1, const float* __restrict__ w,
                                                const float* __restrict__ bias, float* __restrict__ c2) {
    __shared__ float fin[3][128];
    int t = blockIdx.x, b = blockIdx.y, o = threadIdx.x;
    for (int i = threadIdx.x; i < 384; i += 128) {
        int kk = i >> 7, ci = i & 127;
        fin[kk][ci] = c1[(b * 34 + t + kk) * 128 + ci];
    }
    __syncthreads();
    float acc = bias[o];
    for (int kk = 0; kk < 3; kk++)
        for (int ci = 0; ci < 128; ci++)
            acc = fmaf(fin[kk][ci], w[o * 384 + ci * 3 + kk], acc);
    c2[(b * 32 + t) * 128 + o] = tanh_(acc);
}

__global__ __launch_bounds__(128) void k_fd(const float* __restrict__ c2, const float* __restrict__ w1,
                                            const float* __restrict__ b1, const float* __restrict__ w2,
                                            const float* __restrict__ b2, float* __restrict__ cc) {
    __shared__ float a0[128], a1s[128];
    int t = blockIdx.x, b = blockIdx.y, o = threadIdx.x;
    a0[o] = c2[(b * 32 + t) * 128 + o];
    __syncthreads();
    float acc = b1[o];
    for (int k = 0; k < 128; k++) acc = fmaf(a0[k], w1[o * 128 + k], acc);
    a1s[o] = tanh_(acc);
    __syncthreads();
    float acc2 = b2[o];
    for (int k = 0; k < 128; k++) acc2 = fmaf(a1s[k], w2[o * 128 + k], acc2);
    cc[(b * 32 + t) * 128 + o] = tanh_(acc2);
}

// cpart[b][fr][192] = grub_wih[:,384:512] @ c[b][fr] + grub_bih
__global__ __launch_bounds__(192) void k_cpart(const float* __restrict__ cc, const float* __restrict__ wihB,
                                               const float* __restrict__ bihB, float* __restrict__ cpart) {
    __shared__ float cl[128];
    int fr = blockIdx.x, b = blockIdx.y, o = threadIdx.x;
    if (o < 128) cl[o] = cc[(b * 32 + fr) * 128 + o];
    __syncthreads();
    float acc = bihB[o];
    for (int k = 0; k < 128; k++) acc = fmaf(cl[k], wihB[o * 512 + 384 + k], acc);
    cpart[((size_t)b * 32 + fr) * 192 + o] = acc;
}

// ---------------- init: clear stale tags in exchange buffer ----------------
__global__ __launch_bounds__(256) void k_init(u64* hEx) {
    hEx[blockIdx.x * 256 + threadIdx.x] = 0ULL;
}

// ---------------- GRU-A input projection GEMM ----------------
__global__ __launch_bounds__(256) void k_gemm(const int* __restrict__ signals, const float* __restrict__ semb,
                                              const float* __restrict__ c, const u16* __restrict__ wih,
                                              const float* __restrict__ bih, u16* __restrict__ xp) {
    __shared__ u16 As[64][40];
    __shared__ u16 Bs[64][40];
    int m0 = blockIdx.x * 64, n0 = blockIdx.y * 64;
    int tid = threadIdx.x;
    int r = tid >> 2, kc = tid & 3;
    int lane = tid & 63, wv = tid >> 6;
    int wr = wv >> 1, wc = wv & 1;
    int mrow = m0 + r;
    int b = mrow / S_LEN, s = mrow % S_LEN;
    const int* sigrow = signals + mrow * 3;
    const float* crow = c + ((size_t)(b * 32) + s / 160) * 128;
    f32x4 acc[2][2];
#pragma unroll
    for (int i = 0; i < 2; i++)
#pragma unroll
        for (int j = 0; j < 2; j++) { acc[i][j][0] = 0.f; acc[i][j][1] = 0.f; acc[i][j][2] = 0.f; acc[i][j][3] = 0.f; }
    for (int k0 = 0; k0 < 512; k0 += 32) {
        int k = k0 + kc * 8;
        float v[8];
        if (k < 384) {
            int idx = sigrow[k >> 7];
            const float* src = semb + idx * 128 + (k & 127);
#pragma unroll
            for (int j = 0; j < 8; j++) v[j] = src[j];
        } else {
            const float* src = crow + (k - 384);
#pragma unroll
            for (int j = 0; j < 8; j++) v[j] = src[j];
        }
        u32 pk[4];
#pragma unroll
        for (int j = 0; j < 4; j++) pk[j] = (u32)f2bf(v[2 * j]) | ((u32)f2bf(v[2 * j + 1]) << 16);
        *(uint4*)&As[r][kc * 8] = *(uint4*)pk;
        *(uint4*)&Bs[r][kc * 8] = *(const uint4*)&wih[(size_t)(n0 + r) * 512 + k];
        __syncthreads();
        bf16x8 af[2], bfr[2];
#pragma unroll
        for (int mi = 0; mi < 2; mi++) af[mi] = *(const bf16x8*)&As[wr * 32 + mi * 16 + (lane & 15)][(lane >> 4) * 8];
#pragma unroll
        for (int ni = 0; ni < 2; ni++) bfr[ni] = *(const bf16x8*)&Bs[wc * 32 + ni * 16 + (lane & 15)][(lane >> 4) * 8];
#pragma unroll
        for (int mi = 0; mi < 2; mi++)
#pragma unroll
            for (int ni = 0; ni < 2; ni++)
                acc[mi][ni] = __builtin_amdgcn_mfma_f32_16x16x32_bf16(af[mi], bfr[ni], acc[mi][ni], 0, 0, 0);
        __syncthreads();
    }
#pragma unroll
    for (int mi = 0; mi < 2; mi++)
#pragma unroll
        for (int ni = 0; ni < 2; ni++) {
            int row = m0 + wr * 32 + mi * 16 + (lane >> 4) * 4;
            int col = n0 + wc * 32 + ni * 16 + (lane & 15);
            float bias = bih[col];
#pragma unroll
            for (int i = 0; i < 4; i++)
                xp[(size_t)(row + i) * GA + col] = f2bf(acc[mi][ni][i] + bias);
        }
}

// ---------------- the serial GRU kernel ----------------
// 8 WGs/batch, weights in VGPRs, self-tagged single-store exchange.
struct __align__(16) SMemS {
    float cpl[32 * 26];    // cpart slice per frame
    float bhhA[144];
    float bhhB[24];
    float hrep[2][4 * 104]; // hA K-chunked (4 x 96, pad 104), parity-doubled
    float hxB[2][72];       // hB (0..31 at 0, 32..63 at 36), parity-doubled
    float xpb[2 * 144];     // xp double buffer for owned gate rows
    float redA[4 * 148];    // [kc][row]
    float redBy[8 * 26];
    float redBh[2 * 26];
    int dead;
};

__global__ __launch_bounds__(576) void k_serial(const float* __restrict__ whhA, const float* __restrict__ bhhA,
                                                const float* __restrict__ wihB, const float* __restrict__ whhB,
                                                const float* __restrict__ bhhB, const u16* __restrict__ xp,
                                                const float* __restrict__ cpart, const float* __restrict__ h0a,
                                                const float* __restrict__ h0b, u64* hEx,
                                                float* __restrict__ yB) {
    __shared__ SMemS s;
    const int blk = blockIdx.x;
    const int b = blk & 15, slice = blk >> 4;   // consecutive blk = same batch -> same XCD tendency
    const int tid = threadIdx.x;

    // ---- weight registers ----
    const int arow = tid >> 2, akc = tid & 3;
    const int GrA = (arow / 48) * 384 + slice * 48 + (arow % 48);
    uint4 wA[12];
#pragma unroll
    for (int j = 0; j < 12; j++) {
        const float* base = whhA + (size_t)GrA * 384 + akc * 96 + j * 8;
        float4 a = *(const float4*)base;
        float4 c = *(const float4*)(base + 4);
        uint2 pa = pack4(a), pc = pack4(c);
        wA[j] = make_uint4(pa.x, pa.y, pc.x, pc.y);
    }
    const int brow2 = tid >> 3, bkc = tid & 7;
    uint4 wBy[6];
    if (tid < 192) {
        const int Gb = (brow2 / 8) * 64 + slice * 8 + (brow2 % 8);
#pragma unroll
        for (int j = 0; j < 6; j++) {
            const float* base = wihB + (size_t)Gb * 512 + bkc * 48 + j * 8;
            float4 a = *(const float4*)base;
            float4 c = *(const float4*)(base + 4);
            uint2 pa = pack4(a), pc = pack4(c);
            wBy[j] = make_uint4(pa.x, pa.y, pc.x, pc.y);
        }
    }
    const int jB = tid - 192, brow3 = jB >> 1, bk = jB & 1;
    uint4 wBh[4];
    if (tid >= 192 && tid < 240) {
        const int Gb = (brow3 / 8) * 64 + slice * 8 + (brow3 % 8);
#pragma unroll
        for (int j = 0; j < 4; j++) {
            const float* base = whhB + (size_t)Gb * 64 + bk * 32 + j * 8;
            float4 a = *(const float4*)base;
            float4 c = *(const float4*)(base + 4);
            uint2 pa = pack4(a), pc = pack4(c);
            wBh[j] = make_uint4(pa.x, pa.y, pc.x, pc.y);
        }
    }

    // ---- LDS fills ----
    for (int i = tid; i < 32 * 24; i += 576) {
        int fr = i / 24, rw = i % 24;
        int Gb = (rw / 8) * 64 + slice * 8 + (rw % 8);
        s.cpl[fr * 26 + rw] = cpart[((size_t)b * 32 + fr) * 192 + Gb];
    }
    if (tid < 144) {
        int G = (tid / 48) * 384 + slice * 48 + (tid % 48);
        s.bhhA[tid] = bhhA[G];
    } else if (tid < 168) {
        int j = tid - 144;
        int Gb = (j / 8) * 64 + slice * 8 + (j % 8);
        s.bhhB[j] = bhhB[Gb];
    }
    if (tid < 384) {
        s.hrep[0][(tid / 96) * 104 + (tid % 96)] = h0a[b * 384 + tid];
    } else if (tid < 448) {
        int u = tid - 384;
        s.hxB[0][u + (u >= 32 ? 4 : 0)] = h0b[b * 64 + u];
    }
    const int prow = tid - 64;
    const int GpR = (tid >= 64 && tid < 208) ? ((prow / 48) * 384 + slice * 48 + (prow % 48)) : 0;
    if (tid >= 64 && tid < 208)
        s.xpb[prow] = bf2f(xp[((size_t)b * S_LEN) * GA + GpR]);
    if (tid == 0) s.dead = 0;

    // gate-state registers
    float hprA = 0.f, hprB = 0.f;
    if (tid < 48) hprA = h0a[b * 384 + slice * 48 + tid];
    else if (tid < 56) hprB = h0b[b * 64 + slice * 8 + (tid - 48)];
    __syncthreads();

    for (int t = 0; t <= S_LEN; ++t) {
        const bool hasA = (t < S_LEN), hasB = (t > 0);
        const int p = t & 1, p2 = p ^ 1;
        // xp(t+1) prefetch issue
        u16 xpr = 0;
        const bool pref = hasA && tid >= 64 && tid < 208 && (t + 1 < S_LEN);
        if (pref) xpr = xp[((size_t)b * S_LEN + t + 1) * GA + GpR];
        // A matvec from registers
        if (hasA) {
            const float4* hp = (const float4*)(s.hrep[p] + akc * 104);
            float s0 = 0, s1 = 0, s2 = 0, s3 = 0;
#pragma unroll
            for (int i = 0; i < 12; i++) {
                uint4 wv = wA[i];
                float4 h0 = hp[2 * i], h1 = hp[2 * i + 1];
                s0 = fmaf(blo(wv.x), h0.x, s0); s1 = fmaf(bhi(wv.x), h0.y, s1);
                s2 = fmaf(blo(wv.y), h0.z, s2); s3 = fmaf(bhi(wv.y), h0.w, s3);
                s0 = fmaf(blo(wv.z), h1.x, s0); s1 = fmaf(bhi(wv.z), h1.y, s1);
                s2 = fmaf(blo(wv.w), h1.z, s2); s3 = fmaf(bhi(wv.w), h1.w, s3);
            }
            s.redA[akc * 148 + arow] = (s0 + s1) + (s2 + s3);
        }
        // B matvecs
        if (hasB) {
            if (tid < 192) {
                const float4* hp = (const float4*)(s.hrep[p] + (bkc >> 1) * 104 + (bkc & 1) * 48);
                float s0 = 0, s1 = 0, s2 = 0, s3 = 0;
#pragma unroll
                for (int i = 0; i < 6; i++) {
                    uint4 wv = wBy[i];
                    float4 h0 = hp[2 * i], h1 = hp[2 * i + 1];
                    s0 = fmaf(blo(wv.x), h0.x, s0); s1 = fmaf(bhi(wv.x), h0.y, s1);
                    s2 = fmaf(blo(wv.y), h0.z, s2); s3 = fmaf(bhi(wv.y), h0.w, s3);
                    s0 = fmaf(blo(wv.z), h1.x, s0); s1 = fmaf(bhi(wv.z), h1.y, s1);
                    s2 = fmaf(blo(wv.w), h1.z, s2); s3 = fmaf(bhi(wv.w), h1.w, s3);
                }
                s.redBy[bkc * 26 + brow2] = (s0 + s1) + (s2 + s3);
            } else if (tid < 240) {
                const float4* hp = (const float4*)(s.hxB[p] + bk * 36);
                float s0 = 0, s1 = 0, s2 = 0, s3 = 0;
#pragma unroll
                for (int i = 0; i < 4; i++) {
                    uint4 wv = wBh[i];
                    float4 h0 = hp[2 * i], h1 = hp[2 * i + 1];
                    s0 = fmaf(blo(wv.x), h0.x, s0); s1 = fmaf(bhi(wv.x), h0.y, s1);
                    s2 = fmaf(blo(wv.y), h0.z, s2); s3 = fmaf(bhi(wv.y), h0.w, s3);
                    s0 = fmaf(blo(wv.z), h1.x, s0); s1 = fmaf(bhi(wv.z), h1.y, s1);
                    s2 = fmaf(blo(wv.w), h1.z, s2); s3 = fmaf(bhi(wv.w), h1.w, s3);
                }
                s.redBh[bk * 26 + brow3] = (s0 + s1) + (s2 + s3);
            }
        }
        __syncthreads();  // B1: reductions ready, hrep/hxB[p] consumed

        const u32 tagw = (u32)(t + 1) << 16;
        const size_t exb2 = ((size_t)(b * 2 + p2) * 8) * 56;
        if (tid < 48) {
            // ---- A gate ----
            if (hasA) {
                int u = tid;
                float pr = s.redA[u] + s.redA[148 + u] + s.redA[296 + u] + s.redA[444 + u] + s.bhhA[u];
                float pz = s.redA[48 + u] + s.redA[148 + 48 + u] + s.redA[296 + 48 + u] + s.redA[444 + 48 + u] + s.bhhA[48 + u];
                float pn = s.redA[96 + u] + s.redA[148 + 96 + u] + s.redA[296 + 96 + u] + s.redA[444 + 96 + u] + s.bhhA[96 + u];
                const float* xb = s.xpb + p * 144;
                float rg = sigm(xb[u] + pr);
                float zg = sigm(xb[48 + u] + pz);
                float ng = tanh_(xb[96 + u] + rg * pn);
                float hnew = (1.f - zg) * ng + zg * hprA;
                hprA = hnew;
                int g = slice * 48 + u;
                s.hrep[p2][(g / 96) * 104 + (g % 96)] = hnew;
                u32 bits = __float_as_uint(hnew);
                u64 w = ((u64)(tagw | (bits >> 16)) << 32) | (u64)(tagw | (bits & 0xffffu));
                __hip_atomic_store(hEx + exb2 + slice * 56 + u, w, __ATOMIC_RELAXED, __HIP_MEMORY_SCOPE_AGENT);
            }
        } else if (tid < 56) {
            // ---- B gate (computes hB(t-1)) ----
            int u = tid - 48;
            float hbnew = hprB;
            if (hasB) {
                float xr = 0, xz = 0, xn = 0;
#pragma unroll
                for (int j = 0; j < 8; j++) {
                    xr += s.redBy[j * 26 + u];
                    xz += s.redBy[j * 26 + 8 + u];
                    xn += s.redBy[j * 26 + 16 + u];
                }
                int fr = (t - 1) / 160;
                const float* cp = s.cpl + fr * 26;
                xr += cp[u]; xz += cp[8 + u]; xn += cp[16 + u];
                float hr = s.redBh[u] + s.redBh[26 + u] + s.bhhB[u];
                float hz = s.redBh[8 + u] + s.redBh[26 + 8 + u] + s.bhhB[8 + u];
                float hn = s.redBh[16 + u] + s.redBh[26 + 16 + u] + s.bhhB[16 + u];
                float rg = sigm(xr + hr);
                float zg = sigm(xz + hz);
                float ng = tanh_(xn + rg * hn);
                hbnew = (1.f - zg) * ng + zg * hprB;
                hprB = hbnew;
                yB[((size_t)b * S_LEN + (t - 1)) * UB + slice * 8 + u] = hbnew;
            }
            if (hasA) {
                int gb = slice * 8 + u;
                s.hxB[p2][gb + (gb >= 32 ? 4 : 0)] = hbnew;
                u32 bits = __float_as_uint(hbnew);
                u64 w = ((u64)(tagw | (bits >> 16)) << 32) | (u64)(tagw | (bits & 0xffffu));
                __hip_atomic_store(hEx + exb2 + slice * 56 + 48 + u, w, __ATOMIC_RELAXED, __HIP_MEMORY_SCOPE_AGENT);
            }
        } else if (tid >= 64 && tid < 456 && hasA) {
            // ---- pollers: fetch other 7 WGs' values ----
            if (pref) s.xpb[p2 * 144 + prow] = bf2f(xpr);
            int pp = tid - 64, val = pp % 56, ro7 = pp / 56;
            int role = ro7 + (ro7 >= slice ? 1 : 0);
            u64 w = 0;
            if (!s.dead) {
                const u64* ptr = hEx + exb2 + role * 56 + val;
                const u32 tg = (u32)(t + 1) & 0xffffu;
                int cnt = 0;
                for (;;) {
                    w = __hip_atomic_load(ptr, __ATOMIC_RELAXED, __HIP_MEMORY_SCOPE_AGENT);
                    if (((u32)(w >> 16) & 0xffffu) == tg && (u32)(w >> 48) == tg) break;
                    if (++cnt > CAPP) { s.dead = 1; break; }
                }
            }
            float v = __uint_as_float((u32)(w & 0xffffu) | ((u32)(w >> 32) << 16));
            if (val < 48) {
                int g = role * 48 + val;
                s.hrep[p2][(g / 96) * 104 + (g % 96)] = v;
            } else {
                int gb = role * 8 + (val - 48);
                s.hxB[p2][gb + (gb >= 32 ? 4 : 0)] = v;
            }
        }
        if (hasA) __syncthreads();  // B2: hrep/hxB[p2] ready
    }
}

// ---------------- dual FC + log_softmax ----------------
__global__ __launch_bounds__(256) void k_fc(const float* __restrict__ yB, const float* __restrict__ w1,
                                            const float* __restrict__ b1, const float* __restrict__ w2,
                                            const float* __restrict__ b2, const float* __restrict__ alpha,
                                            const float* __restrict__ beta, float* __restrict__ out) {
    __shared__ float yb[4][64];
    __shared__ float vb[4][256];
    int tid = threadIdx.x;
    size_t r0 = (size_t)blockIdx.x * 4;
    { int r = tid >> 6, k = tid & 63; yb[r][k] = yB[(r0 + r) * 64 + k]; }
    __syncthreads();
    int o = tid;
    float a1[4] = {0, 0, 0, 0}, a2[4] = {0, 0, 0, 0};
    for (int k = 0; k < 64; k += 4) {
        float4 u = *(const float4*)(w1 + o * 64 + k);
        float4 v = *(const float4*)(w2 + o * 64 + k);
#pragma unroll
        for (int r = 0; r < 4; r++) {
            float y0 = yb[r][k], y1 = yb[r][k + 1], y2 = yb[r][k + 2], y3 = yb[r][k + 3];
            a1[r] = fmaf(u.x, y0, fmaf(u.y, y1, fmaf(u.z, y2, fmaf(u.w, y3, a1[r]))));
            a2[r] = fmaf(v.x, y0, fmaf(v.y, y1, fmaf(v.z, y2, fmaf(v.w, y3, a2[r]))));
        }
    }
    float al = alpha[o], be = beta[o], c1 = b1[o], c2 = b2[o];
#pragma unroll
    for (int r = 0; r < 4; r++)
        vb[r][o] = al * tanh_(a1[r] + c1) + be * tanh_(a2[r] + c2);
    __syncthreads();
    int wv = tid >> 6, l = tid & 63;
    float x0 = vb[wv][l], x1 = vb[wv][64 + l], x2 = vb[wv][128 + l], x3 = vb[wv][192 + l];
    float m = fmaxf(fmaxf(x0, x1), fmaxf(x2, x3));
#pragma unroll
    for (int off = 1; off < 64; off <<= 1) m = fmaxf(m, __shfl_xor(m, off));
    float sum = __expf(x0 - m) + __expf(x1 - m) + __expf(x2 - m) + __expf(x3 - m);
#pragma unroll
    for (int off = 1; off < 64; off <<= 1) sum += __shfl_xor(sum, off);
    float lse = m + __logf(sum);
    float* po = out + (r0 + wv) * 256;
    po[l] = x0 - lse;
    po[64 + l] = x1 - lse;
    po[128 + l] = x2 - lse;
    po[192 + l] = x3 - lse;
}

extern "C" void kernel_launch(void* const* d_in, const int* in_sizes, int n_in,
                              void* d_out, int out_size, void* d_ws, size_t ws_size,
                              hipStream_t stream) {
    const float* features = (const float*)d_in[0];
    const int* periods = (const int*)d_in[1];
    const int* signals = (const int*)d_in[2];
    const float* gruA0 = (const float*)d_in[3];
    const float* gruB0 = (const float*)d_in[4];
    const float* period_emb = (const float*)d_in[5];
    const float* signal_emb = (const float*)d_in[6];
    const float* conv1_w = (const float*)d_in[7];
    const float* conv1_b = (const float*)d_in[8];
    const float* conv2_w = (const float*)d_in[9];
    const float* conv2_b = (const float*)d_in[10];
    const float* fd1_w = (const float*)d_in[11];
    const float* fd1_b = (const float*)d_in[12];
    const float* fd2_w = (const float*)d_in[13];
    const float* fd2_b = (const float*)d_in[14];
    const float* grua_wih = (const float*)d_in[15];
    const float* grua_whh = (const float*)d_in[16];
    const float* grua_bih = (const float*)d_in[17];
    const float* grua_bhh = (const float*)d_in[18];
    const float* grub_wih = (const float*)d_in[19];
    const float* grub_whh = (const float*)d_in[20];
    const float* grub_bih = (const float*)d_in[21];
    const float* grub_bhh = (const float*)d_in[22];
    const float* fc1_w = (const float*)d_in[23];
    const float* fc1_b = (const float*)d_in[24];
    const float* fc2_w = (const float*)d_in[25];
    const float* fc2_b = (const float*)d_in[26];
    const float* alpha = (const float*)d_in[27];
    const float* beta = (const float*)d_in[28];
    float* out = (float*)d_out;

    char* ws = (char*)d_ws;
    size_t off = 0;
    auto alloc = [&](size_t bytes) { void* p = ws + off; off += (bytes + 255) & ~(size_t)255; return p; };
    u16* xp = (u16*)alloc((size_t)16 * 5120 * 1152 * 2);
    u16* wihA = (u16*)alloc((size_t)1152 * 512 * 2);
    float* c1 = (float*)alloc((size_t)16 * 34 * 128 * 4);
    float* c2 = (float*)alloc((size_t)16 * 32 * 128 * 4);
    float* cc = (float*)alloc((size_t)16 * 32 * 128 * 4);
    float* cpart = (float*)alloc((size_t)16 * 32 * 192 * 4);
    float* yB = (float*)alloc((size_t)16 * 5120 * 64 * 4);
    u64* hEx = (u64*)alloc((size_t)16 * 2 * 8 * 56 * 8);

    k_cvt<<<dim3(2304), dim3(256), 0, stream>>>(grua_wih, wihA);
    k_frame1<<<dim3(34, 16), dim3(128), 0, stream>>>(features, periods, period_emb, conv1_w, conv1_b, c1);
    k_frame2<<<dim3(32, 16), dim3(128), 0, stream>>>(c1, conv2_w, conv2_b, c2);
    k_fd<<<dim3(32, 16), dim3(128), 0, stream>>>(c2, fd1_w, fd1_b, fd2_w, fd2_b, cc);
    k_cpart<<<dim3(32, 16), dim3(192), 0, stream>>>(cc, grub_wih, grub_bih, cpart);
    k_init<<<dim3(56), dim3(256), 0, stream>>>(hEx);
    k_gemm<<<dim3(1280, 18), dim3(256), 0, stream>>>(signals, signal_emb, cc, wihA, grua_bih, xp);
    k_serial<<<dim3(128), dim3(576), 0, stream>>>(grua_whh, grua_bhh, grub_wih, grub_whh, grub_bhh,
                                                  xp, cpart, gruA0, gruB0, hEx, yB);
    k_fc<<<dim3(20480), dim3(256), 0, stream>>>(yB, fc1_w, fc1_b, fc2_w, fc2_b, alpha, beta, out);
}